// Round 2
// baseline (5242.458 us; speedup 1.0000x reference)
//
#include <hip/hip_runtime.h>

typedef _Float16 f16x8 __attribute__((ext_vector_type(8)));
typedef _Float16 f16x4 __attribute__((ext_vector_type(4)));
typedef float f32x4 __attribute__((ext_vector_type(4)));

#define NB 4096  // batch

__device__ __forceinline__ void gload16(const void* g, void* l) {
    __builtin_amdgcn_global_load_lds(
        (const __attribute__((address_space(1))) unsigned int*)g,
        (__attribute__((address_space(3))) unsigned int*)l, 16, 0, 0);
}

// ---------------- transpose + fp16-split of initial x: [4096 f][4096 b] -> Xt[b][f] h/l
__global__ __launch_bounds__(256) void tsplit_kernel(const float* __restrict__ X,
                                                     _Float16* __restrict__ Oh,
                                                     _Float16* __restrict__ Ol) {
    __shared__ float t[64][65];
    const int f0 = blockIdx.x * 64, b0 = blockIdx.y * 64;
    const int tid = threadIdx.x;
    const int jj = tid & 63, i0 = tid >> 6;
#pragma unroll
    for (int p = 0; p < 16; ++p) {
        int i = p * 4 + i0;
        t[i][jj] = X[(size_t)(f0 + i) * NB + b0 + jj];
    }
    __syncthreads();
#pragma unroll
    for (int p = 0; p < 16; ++p) {
        int b = p * 4 + i0;
        float v = t[jj][b];
        size_t idx = (size_t)(b0 + b) * 4096 + f0 + jj;
        _Float16 h = (_Float16)v;
        Oh[idx] = h;
        Ol[idx] = (_Float16)((v - (float)h) * 2048.0f);
    }
}

// ---------------- fp16-split of a weight matrix (elementwise)
__global__ __launch_bounds__(256) void splitw_kernel(const float* __restrict__ W,
                                                     _Float16* __restrict__ Wh,
                                                     _Float16* __restrict__ Wl, long n4) {
    long i = (long)blockIdx.x * 256 + threadIdx.x;
    const long stride = (long)gridDim.x * 256;
    for (; i < n4; i += stride) {
        float4 w = ((const float4*)W)[i];
        float vs[4] = {w.x, w.y, w.z, w.w};
        f16x4 h, l;
#pragma unroll
        for (int j = 0; j < 4; ++j) {
            _Float16 hh = (_Float16)vs[j];
            h[j] = hh;
            l[j] = (_Float16)((vs[j] - (float)hh) * 2048.0f);
        }
        ((f16x4*)Wh)[i] = h;
        ((f16x4*)Wl)[i] = l;
    }
}

// ---------------- pipelined GEMM: C[batch][M] = Xt @ W^T, fp16x2-split 3-MFMA
// Tile 128(batch) x 256(feat), BK=32, 512 thr = 8 waves (2M x 4N), per-wave 64x64.
// Triple-buffered LDS (depth-2 prefetch, counted vmcnt), T2 XOR swizzle, T5 setprio.
__global__ __launch_bounds__(512, 2) void gemm3p_kernel(
    const _Float16* __restrict__ Ah, const _Float16* __restrict__ Al,
    const _Float16* __restrict__ Bh, const _Float16* __restrict__ Bl,
    float* __restrict__ C, int K, int M, int do_relu) {
    // per buffer: A h 8KB | A l 8KB | B h 16KB | B l 16KB = 48KB; x3 = 144KB
    __shared__ __align__(16) char lds[3][49152];

    const int tid = threadIdx.x;
    // XCD-aware bijective block swizzle (nwg % 8 == 0 for all our grids)
    const int gx = gridDim.x;
    const int nwg = gx * gridDim.y;
    int bid = blockIdx.y * gx + blockIdx.x;
    bid = (bid & 7) * (nwg >> 3) + (bid >> 3);
    const int col0 = (bid % gx) * 256;  // feature cols
    const int row0 = (bid / gx) * 128;  // batch rows

    const int wid = tid >> 6, lane = tid & 63;
    const int wm = wid >> 2, wn = wid & 3;  // 2 x 4 waves
    const int lr = lane & 15;
    // read-side swizzle: per-lane 16B chunk within a 64B row: chunk' = c ^ ((row>>1)&3)
    const int rdoff = (((lane >> 4) ^ ((lane >> 1) & 3)) << 4);

    f32x4 acc[4][4] = {};
    f32x4 accx[4][4] = {};

    // staging: linear LDS dest (tid*16); inverse-swizzled global source chunk
    const int srow = tid >> 2;                     // local row 0..127
    const int scl = (tid & 3) ^ ((tid >> 3) & 3);  // logical k-chunk for this dest
    const size_t sk = (size_t)K;
    const _Float16* gA_h = Ah + (size_t)(row0 + srow) * sk + scl * 8;
    const _Float16* gA_l = Al + (size_t)(row0 + srow) * sk + scl * 8;
    const _Float16* gB_h0 = Bh + (size_t)(col0 + srow) * sk + scl * 8;
    const _Float16* gB_h1 = Bh + (size_t)(col0 + 128 + srow) * sk + scl * 8;
    const _Float16* gB_l0 = Bl + (size_t)(col0 + srow) * sk + scl * 8;
    const _Float16* gB_l1 = Bl + (size_t)(col0 + 128 + srow) * sk + scl * 8;
    const int ldsA = tid * 16;

#define STAGE(bufi, t2)                                   \
    do {                                                  \
        char* Lb = lds[bufi];                             \
        const size_t go = (size_t)(t2) * 32;              \
        gload16(gA_h + go, Lb + ldsA);                    \
        gload16(gA_l + go, Lb + 8192 + ldsA);             \
        gload16(gB_h0 + go, Lb + 16384 + ldsA);           \
        gload16(gB_h1 + go, Lb + 24576 + ldsA);           \
        gload16(gB_l0 + go, Lb + 32768 + ldsA);           \
        gload16(gB_l1 + go, Lb + 40960 + ldsA);           \
    } while (0)

    const int NT = K / 32;
    STAGE(0, 0);
    STAGE(1, 1);

    for (int t = 0; t < NT; ++t) {
        if (t < NT - 1) {
            asm volatile("s_waitcnt vmcnt(6)" ::: "memory");  // tile t landed; t+1 in flight
        } else {
            asm volatile("s_waitcnt vmcnt(0)" ::: "memory");
        }
        __builtin_amdgcn_s_barrier();
        asm volatile("" ::: "memory");  // no LDS access moves above the barrier
        if (t + 2 < NT) STAGE((t + 2) % 3, t + 2);

        const char* Lb = lds[t % 3];
        const char* sAh_ = Lb;
        const char* sAl_ = Lb + 8192;
        const char* sBh_ = Lb + 16384;
        const char* sBl_ = Lb + 32768;

        // A fragments (8 reads) + B pairs 0,1 (4 reads)
        f16x8 ah[4], al[4], bh[4], bl[4];
#pragma unroll
        for (int mi = 0; mi < 4; ++mi) {
            const int ra = wm * 64 + mi * 16 + lr;
            ah[mi] = *(const f16x8*)(sAh_ + ra * 64 + rdoff);
            al[mi] = *(const f16x8*)(sAl_ + ra * 64 + rdoff);
        }
#pragma unroll
        for (int ni = 0; ni < 2; ++ni) {
            const int rb = wn * 64 + ni * 16 + lr;
            bh[ni] = *(const f16x8*)(sBh_ + rb * 64 + rdoff);
            bl[ni] = *(const f16x8*)(sBl_ + rb * 64 + rdoff);
        }
#pragma unroll
        for (int ni = 0; ni < 4; ++ni) {
            if (ni < 3) {
                asm volatile("s_waitcnt lgkmcnt(2)" ::: "memory");  // pair ni ready, ni+1 in flight
            } else {
                asm volatile("s_waitcnt lgkmcnt(0)" ::: "memory");
            }
            if (ni < 2) {  // issue pair ni+2
                const int rb = wn * 64 + (ni + 2) * 16 + lr;
                bh[ni + 2] = *(const f16x8*)(sBh_ + rb * 64 + rdoff);
                bl[ni + 2] = *(const f16x8*)(sBl_ + rb * 64 + rdoff);
            }
            __builtin_amdgcn_sched_barrier(0);
            __builtin_amdgcn_s_setprio(1);
#pragma unroll
            for (int mi = 0; mi < 4; ++mi) {
                acc[mi][ni] = __builtin_amdgcn_mfma_f32_16x16x32_f16(ah[mi], bh[ni], acc[mi][ni], 0, 0, 0);
                accx[mi][ni] = __builtin_amdgcn_mfma_f32_16x16x32_f16(ah[mi], bl[ni], accx[mi][ni], 0, 0, 0);
                accx[mi][ni] = __builtin_amdgcn_mfma_f32_16x16x32_f16(al[mi], bh[ni], accx[mi][ni], 0, 0, 0);
            }
            __builtin_amdgcn_s_setprio(0);
        }
    }
#undef STAGE

    // epilogue: combine split accumulators, optional relu, store fp32
#pragma unroll
    for (int mi = 0; mi < 4; ++mi)
#pragma unroll
        for (int ni = 0; ni < 4; ++ni) {
            int colx = col0 + wn * 64 + ni * 16 + lr;
            int rowb = row0 + wm * 64 + mi * 16 + ((lane >> 4) << 2);
#pragma unroll
            for (int r = 0; r < 4; ++r) {
                float v = acc[mi][ni][r] + accx[mi][ni][r] * (1.0f / 2048.0f);
                if (do_relu) v = fmaxf(v, 0.0f);
                C[(size_t)(rowb + r) * M + colx] = v;
            }
        }
}

// ---------------- small-M GEMM (layer 3, M=1024): proven 128x128 single-buffer kernel
__global__ __launch_bounds__(256, 2) void gemm3_kernel(
    const _Float16* __restrict__ Ah, const _Float16* __restrict__ Al,
    const _Float16* __restrict__ Bh, const _Float16* __restrict__ Bl,
    float* __restrict__ C, int K, int M, int do_relu) {
    __shared__ __align__(16) _Float16 sAh[128 * 32];
    __shared__ __align__(16) _Float16 sAl[128 * 32];
    __shared__ __align__(16) _Float16 sBh[128 * 32];
    __shared__ __align__(16) _Float16 sBl[128 * 32];

    const int tid = threadIdx.x;
    const int row0 = blockIdx.y * 128;
    const int col0 = blockIdx.x * 128;
    const int wid = tid >> 6, lane = tid & 63;
    const int wm = wid >> 1, wn = wid & 1;
    const int lr = lane & 15, lk = (lane >> 4) * 8;

    f32x4 acc[4][4] = {};
    f32x4 accx[4][4] = {};

    const int o0 = tid * 16;
    const int o1 = o0 + 4096;
    const int r0 = o0 >> 6, c0 = o0 & 63;
    const int r1 = o1 >> 6, c1 = o1 & 63;
    const size_t sk = (size_t)K * 2;

    const char* gAh0 = (const char*)Ah + (size_t)(row0 + r0) * sk + c0;
    const char* gAh1 = (const char*)Ah + (size_t)(row0 + r1) * sk + c1;
    const char* gAl0 = (const char*)Al + (size_t)(row0 + r0) * sk + c0;
    const char* gAl1 = (const char*)Al + (size_t)(row0 + r1) * sk + c1;
    const char* gBh0 = (const char*)Bh + (size_t)(col0 + r0) * sk + c0;
    const char* gBh1 = (const char*)Bh + (size_t)(col0 + r1) * sk + c1;
    const char* gBl0 = (const char*)Bl + (size_t)(col0 + r0) * sk + c0;
    const char* gBl1 = (const char*)Bl + (size_t)(col0 + r1) * sk + c1;

    for (int k0 = 0; k0 < K; k0 += 32) {
        __syncthreads();
        gload16(gAh0, (char*)sAh + o0);
        gload16(gAh1, (char*)sAh + o1);
        gload16(gAl0, (char*)sAl + o0);
        gload16(gAl1, (char*)sAl + o1);
        gload16(gBh0, (char*)sBh + o0);
        gload16(gBh1, (char*)sBh + o1);
        gload16(gBl0, (char*)sBl + o0);
        gload16(gBl1, (char*)sBl + o1);
        gAh0 += 64; gAh1 += 64; gAl0 += 64; gAl1 += 64;
        gBh0 += 64; gBh1 += 64; gBl0 += 64; gBl1 += 64;
        __syncthreads();

        f16x8 bh[4], bl[4];
#pragma unroll
        for (int ni = 0; ni < 4; ++ni) {
            int rb = wn * 64 + ni * 16 + lr;
            bh[ni] = *(const f16x8*)&sBh[rb * 32 + lk];
            bl[ni] = *(const f16x8*)&sBl[rb * 32 + lk];
        }
#pragma unroll
        for (int mi = 0; mi < 4; ++mi) {
            int ra = wm * 64 + mi * 16 + lr;
            f16x8 ah = *(const f16x8*)&sAh[ra * 32 + lk];
            f16x8 al = *(const f16x8*)&sAl[ra * 32 + lk];
#pragma unroll
            for (int ni = 0; ni < 4; ++ni) {
                acc[mi][ni] = __builtin_amdgcn_mfma_f32_16x16x32_f16(ah, bh[ni], acc[mi][ni], 0, 0, 0);
                accx[mi][ni] = __builtin_amdgcn_mfma_f32_16x16x32_f16(ah, bl[ni], accx[mi][ni], 0, 0, 0);
                accx[mi][ni] = __builtin_amdgcn_mfma_f32_16x16x32_f16(al, bh[ni], accx[mi][ni], 0, 0, 0);
            }
        }
    }
#pragma unroll
    for (int mi = 0; mi < 4; ++mi)
#pragma unroll
        for (int ni = 0; ni < 4; ++ni) {
            int colx = col0 + wn * 64 + ni * 16 + lr;
            int rowb = row0 + wm * 64 + mi * 16 + (lane >> 4) * 4;
#pragma unroll
            for (int r = 0; r < 4; ++r) {
                float v = acc[mi][ni][r] + accx[mi][ni][r] * (1.0f / 2048.0f);
                if (do_relu) v = fmaxf(v, 0.0f);
                C[(size_t)(rowb + r) * M + colx] = v;
            }
        }
}

// ---------------- kWTA: exact k-th largest of (x - thr[col]) per row via 4x8-bit radix
template <int CNT, bool SOFTMAX>
__global__ __launch_bounds__(256) void kwta_kernel(const float* __restrict__ Cin,
                                                   const float* __restrict__ thr,
                                                   _Float16* __restrict__ Oh,
                                                   _Float16* __restrict__ Ol,
                                                   float* __restrict__ outT, int M, int k) {
    const int row = blockIdx.x, tid = threadIdx.x;
    const float* rp = Cin + (size_t)row * M;
    unsigned uv[CNT];
    float xv[CNT];
#pragma unroll
    for (int i = 0; i < CNT; ++i) {
        int col = i * 256 + tid;
        float x = rp[col];
        float a = x - thr[col];
        unsigned b = __float_as_uint(a);
        uv[i] = (b & 0x80000000u) ? ~b : (b | 0x80000000u);
        xv[i] = x;
    }
    __shared__ int hist[256];
    __shared__ unsigned sel_s;
    __shared__ int kk_s;
    unsigned prefix = 0;
    int kk = k;
#pragma unroll
    for (int pass = 0; pass < 4; ++pass) {
        const int shift = 24 - pass * 8;
        hist[tid] = 0;
        __syncthreads();
#pragma unroll
        for (int i = 0; i < CNT; ++i) {
            bool ok = (pass == 0) || ((uv[i] >> (shift + 8)) == prefix);
            if (ok) atomicAdd(&hist[(uv[i] >> shift) & 255], 1);
        }
        __syncthreads();
        for (int off = 1; off < 256; off <<= 1) {
            int v = hist[tid] + ((tid + off < 256) ? hist[tid + off] : 0);
            __syncthreads();
            hist[tid] = v;
            __syncthreads();
        }
        if (hist[tid] >= kk && (tid == 255 || hist[tid + 1] < kk)) {
            sel_s = (unsigned)tid;
            kk_s = kk - ((tid == 255) ? 0 : hist[tid + 1]);
        }
        __syncthreads();
        prefix = (prefix << 8) | sel_s;
        kk = kk_s;
        __syncthreads();
    }
    const unsigned kth = prefix;
    if (!SOFTMAX) {
#pragma unroll
        for (int i = 0; i < CNT; ++i) {
            int col = i * 256 + tid;
            float v = (uv[i] >= kth) ? xv[i] : 0.0f;
            size_t idx = (size_t)row * M + col;
            _Float16 h = (_Float16)v;
            Oh[idx] = h;
            Ol[idx] = (_Float16)((v - (float)h) * 2048.0f);
        }
    } else {
        float vals[CNT];
        float m = -3.4e38f;
#pragma unroll
        for (int i = 0; i < CNT; ++i) {
            float v = (uv[i] >= kth) ? xv[i] : 0.0f;
            vals[i] = v;
            m = fmaxf(m, v);
        }
        for (int off = 32; off; off >>= 1) m = fmaxf(m, __shfl_xor(m, off));
        __shared__ float redm[4];
        if ((tid & 63) == 0) redm[tid >> 6] = m;
        __syncthreads();
        m = fmaxf(fmaxf(redm[0], redm[1]), fmaxf(redm[2], redm[3]));
        float s = 0.0f, e[CNT];
#pragma unroll
        for (int i = 0; i < CNT; ++i) {
            e[i] = expf(vals[i] - m);
            s += e[i];
        }
        for (int off = 32; off; off >>= 1) s += __shfl_xor(s, off);
        __shared__ float reds[4];
        if ((tid & 63) == 0) reds[tid >> 6] = s;
        __syncthreads();
        s = reds[0] + reds[1] + reds[2] + reds[3];
        float inv = 1.0f / s;
#pragma unroll
        for (int i = 0; i < CNT; ++i)
            outT[(size_t)(i * 256 + tid) * NB + row] = e[i] * inv;
    }
}

extern "C" void kernel_launch(void* const* d_in, const int* in_sizes, int n_in,
                              void* d_out, int out_size, void* d_ws, size_t ws_size,
                              hipStream_t stream) {
    const float* x = (const float*)d_in[0];
    const float* W0 = (const float*)d_in[1];
    const float* thr0 = (const float*)d_in[2];
    const float* W1 = (const float*)d_in[3];
    const float* thr1 = (const float*)d_in[4];
    const float* W2 = (const float*)d_in[5];
    const float* thr2 = (const float*)d_in[6];
    const float* W3 = (const float*)d_in[7];
    const float* thr3 = (const float*)d_in[8];
    float* out = (float*)d_out;

    char* ws = (char*)d_ws;
    size_t off = 0;
    auto alloc = [&](size_t bytes) {
        void* p = ws + off;
        off += (bytes + 255) & ~(size_t)255;
        return p;
    };
    _Float16* Wh = (_Float16*)alloc((size_t)8192 * 8192 * 2);
    _Float16* Wl = (_Float16*)alloc((size_t)8192 * 8192 * 2);
    _Float16* Xh = (_Float16*)alloc((size_t)4096 * 8192 * 2);
    _Float16* Xl = (_Float16*)alloc((size_t)4096 * 8192 * 2);
    _Float16* Yh = (_Float16*)alloc((size_t)4096 * 8192 * 2);
    _Float16* Yl = (_Float16*)alloc((size_t)4096 * 8192 * 2);
    float* C32 = (float*)alloc((size_t)4096 * 8192 * 4);

    tsplit_kernel<<<dim3(64, 64), 256, 0, stream>>>(x, Xh, Xl);

    // layer 0: K=4096, M=8192, relu, k=409
    splitw_kernel<<<4096, 256, 0, stream>>>(W0, Wh, Wl, (long)8192 * 4096 / 4);
    gemm3p_kernel<<<dim3(8192 / 256, NB / 128), 512, 0, stream>>>(Xh, Xl, Wh, Wl, C32, 4096, 8192, 1);
    kwta_kernel<32, false><<<NB, 256, 0, stream>>>(C32, thr0, Yh, Yl, nullptr, 8192, 409);

    // layer 1: K=8192, M=8192, relu, k=409
    splitw_kernel<<<4096, 256, 0, stream>>>(W1, Wh, Wl, (long)8192 * 8192 / 4);
    gemm3p_kernel<<<dim3(8192 / 256, NB / 128), 512, 0, stream>>>(Yh, Yl, Wh, Wl, C32, 8192, 8192, 1);
    kwta_kernel<32, false><<<NB, 256, 0, stream>>>(C32, thr1, Xh, Xl, nullptr, 8192, 409);

    // layer 2: K=8192, M=4096, relu, k=204
    splitw_kernel<<<4096, 256, 0, stream>>>(W2, Wh, Wl, (long)4096 * 8192 / 4);
    gemm3p_kernel<<<dim3(4096 / 256, NB / 128), 512, 0, stream>>>(Xh, Xl, Wh, Wl, C32, 8192, 4096, 1);
    kwta_kernel<16, false><<<NB, 256, 0, stream>>>(C32, thr2, Yh, Yl, nullptr, 4096, 204);

    // layer 3: K=4096, M=1024, no relu, k=51, then softmax -> out [1024][4096]
    splitw_kernel<<<4096, 256, 0, stream>>>(W3, Wh, Wl, (long)1024 * 4096 / 4);
    gemm3_kernel<<<dim3(1024 / 128, NB / 128), 256, 0, stream>>>(Yh, Yl, Wh, Wl, C32, 4096, 1024, 0);
    kwta_kernel<4, true><<<NB, 256, 0, stream>>>(C32, thr3, nullptr, nullptr, out, 1024, 51);
}

// Round 3
// 3293.176 us; speedup vs baseline: 1.5919x; 1.5919x over previous
//
#include <hip/hip_runtime.h>

typedef _Float16 f16x8 __attribute__((ext_vector_type(8)));
typedef _Float16 f16x4 __attribute__((ext_vector_type(4)));
typedef float f32x4 __attribute__((ext_vector_type(4)));

#define NB 4096  // batch

__device__ __forceinline__ void gload16(const void* g, void* l) {
    __builtin_amdgcn_global_load_lds(
        (const __attribute__((address_space(1))) unsigned int*)g,
        (__attribute__((address_space(3))) unsigned int*)l, 16, 0, 0);
}

// ---------------- transpose + fp16-split of initial x: [4096 f][4096 b] -> Xt[b][f] h/l
__global__ __launch_bounds__(256) void tsplit_kernel(const float* __restrict__ X,
                                                     _Float16* __restrict__ Oh,
                                                     _Float16* __restrict__ Ol) {
    __shared__ float t[64][65];
    const int f0 = blockIdx.x * 64, b0 = blockIdx.y * 64;
    const int tid = threadIdx.x;
    const int jj = tid & 63, i0 = tid >> 6;
#pragma unroll
    for (int p = 0; p < 16; ++p) {
        int i = p * 4 + i0;
        t[i][jj] = X[(size_t)(f0 + i) * NB + b0 + jj];
    }
    __syncthreads();
#pragma unroll
    for (int p = 0; p < 16; ++p) {
        int b = p * 4 + i0;
        float v = t[jj][b];
        size_t idx = (size_t)(b0 + b) * 4096 + f0 + jj;
        _Float16 h = (_Float16)v;
        Oh[idx] = h;
        Ol[idx] = (_Float16)((v - (float)h) * 2048.0f);
    }
}

// ---------------- fp16-split of a weight matrix (elementwise)
__global__ __launch_bounds__(256) void splitw_kernel(const float* __restrict__ W,
                                                     _Float16* __restrict__ Wh,
                                                     _Float16* __restrict__ Wl, long n4) {
    long i = (long)blockIdx.x * 256 + threadIdx.x;
    const long stride = (long)gridDim.x * 256;
    for (; i < n4; i += stride) {
        float4 w = ((const float4*)W)[i];
        float vs[4] = {w.x, w.y, w.z, w.w};
        f16x4 h, l;
#pragma unroll
        for (int j = 0; j < 4; ++j) {
            _Float16 hh = (_Float16)vs[j];
            h[j] = hh;
            l[j] = (_Float16)((vs[j] - (float)hh) * 2048.0f);
        }
        ((f16x4*)Wh)[i] = h;
        ((f16x4*)Wl)[i] = l;
    }
}

// ---------------- pipelined GEMM: C[batch][M] = Xt @ W^T, fp16x2-split 3-MFMA
// Tile 128(batch) x 256(feat), BK=32, 512 thr = 8 waves (2M x 4N), per-wave 64x64.
// Triple-buffered LDS, depth-2 prefetch with counted vmcnt, T2 XOR swizzle, T5 setprio.
// Block remap: each generation of 256 co-resident blocks forms a 16x16 supertile
// (A panel 67MB + B panel 134MB fits the 256MB L3 -> B fetched once per supertile).
__global__ __launch_bounds__(512, 2) void gemm3p_kernel(
    const _Float16* __restrict__ Ah, const _Float16* __restrict__ Al,
    const _Float16* __restrict__ Bh, const _Float16* __restrict__ Bl,
    float* __restrict__ C, int K, int M, int do_relu) {
    // per buffer: A h 8KB | A l 8KB | B h 16KB | B l 16KB = 48KB; x3 = 144KB
    __shared__ __align__(16) char lds[3][49152];

    const int tid = threadIdx.x;
    const int gx = gridDim.x;
    // supertile remap: 256 consecutive hw bids -> SC col-tiles x SR row-tiles square
    int bid = blockIdx.y * gx + blockIdx.x;
    const int SC = gx < 16 ? gx : 16;
    const int SR = 256 / SC;
    const int nsc = gx / SC;
    const int s = bid >> 8, w = bid & 255;
    const int col0 = ((s % nsc) * SC + (w % SC)) * 256;  // feature cols
    const int row0 = ((s / nsc) * SR + (w / SC)) * 128;  // batch rows

    const int wid = tid >> 6, lane = tid & 63;
    const int wm = wid >> 2, wn = wid & 3;  // 2 x 4 waves
    const int lr = lane & 15;
    // read-side swizzle: per-lane 16B chunk within a 64B row: chunk' = c ^ ((row>>1)&3)
    const int rdoff = (((lane >> 4) ^ ((lane >> 1) & 3)) << 4);

    f32x4 acc[4][4] = {};
    f32x4 accx[4][4] = {};

    // staging: linear LDS dest (tid*16); inverse-swizzled global source chunk
    const int srow = tid >> 2;                     // local row 0..127
    const int scl = (tid & 3) ^ ((tid >> 3) & 3);  // logical k-chunk for this dest
    const size_t sk = (size_t)K;
    const _Float16* gA_h = Ah + (size_t)(row0 + srow) * sk + scl * 8;
    const _Float16* gA_l = Al + (size_t)(row0 + srow) * sk + scl * 8;
    const _Float16* gB_h0 = Bh + (size_t)(col0 + srow) * sk + scl * 8;
    const _Float16* gB_h1 = Bh + (size_t)(col0 + 128 + srow) * sk + scl * 8;
    const _Float16* gB_l0 = Bl + (size_t)(col0 + srow) * sk + scl * 8;
    const _Float16* gB_l1 = Bl + (size_t)(col0 + 128 + srow) * sk + scl * 8;
    const int ldsA = tid * 16;

#define STAGE_G0(Lb, go) { gload16(gA_h + go, (Lb) + ldsA); gload16(gA_l + go, (Lb) + 8192 + ldsA); }
#define STAGE_G1(Lb, go) { gload16(gB_h0 + go, (Lb) + 16384 + ldsA); gload16(gB_h1 + go, (Lb) + 24576 + ldsA); }
#define STAGE_G2(Lb, go) { gload16(gB_l0 + go, (Lb) + 32768 + ldsA); gload16(gB_l1 + go, (Lb) + 40960 + ldsA); }

    const int NT = K / 32;
    {  // prologue: tiles 0 and 1, 6 loads each in program-order groups
        STAGE_G0(lds[0], 0); STAGE_G1(lds[0], 0); STAGE_G2(lds[0], 0);
        STAGE_G0(lds[1], 32); STAGE_G1(lds[1], 32); STAGE_G2(lds[1], 32);
    }

    for (int t = 0; t < NT; ++t) {
        if (t < NT - 1) {
            asm volatile("s_waitcnt vmcnt(6)" ::: "memory");  // tile t landed; t+1 in flight
        } else {
            asm volatile("s_waitcnt vmcnt(0)" ::: "memory");
        }
        __builtin_amdgcn_s_barrier();
        asm volatile("" ::: "memory");  // keep LDS/VMEM ops below the barrier

        const char* Lb = lds[t % 3];
        char* Ls = lds[(t + 2) % 3];               // stage dest (last read in iter t-1)
        const bool do_stage = (t + 2 < NT);
        const size_t go = (size_t)(t + 2) * 32;

        const char* sAh_ = Lb;
        const char* sAl_ = Lb + 8192;
        const char* sBh_ = Lb + 16384;
        const char* sBl_ = Lb + 32768;

        // A fragments (8 reads) + B pairs 0,1 (4 reads)
        f16x8 ah[4], al[4], bh[4], bl[4];
#pragma unroll
        for (int mi = 0; mi < 4; ++mi) {
            const int ra = wm * 64 + mi * 16 + lr;
            ah[mi] = *(const f16x8*)(sAh_ + ra * 64 + rdoff);
            al[mi] = *(const f16x8*)(sAl_ + ra * 64 + rdoff);
        }
#pragma unroll
        for (int ni = 0; ni < 2; ++ni) {
            const int rb = wn * 64 + ni * 16 + lr;
            bh[ni] = *(const f16x8*)(sBh_ + rb * 64 + rdoff);
            bl[ni] = *(const f16x8*)(sBl_ + rb * 64 + rdoff);
        }
#pragma unroll
        for (int ni = 0; ni < 4; ++ni) {
            if (ni < 3) {
                asm volatile("s_waitcnt lgkmcnt(2)" ::: "memory");  // pair ni ready, next in flight
            } else {
                asm volatile("s_waitcnt lgkmcnt(0)" ::: "memory");  // drain before next barrier
            }
            if (ni < 2) {  // issue pair ni+2
                const int rb = wn * 64 + (ni + 2) * 16 + lr;
                bh[ni + 2] = *(const f16x8*)(sBh_ + rb * 64 + rdoff);
                bl[ni + 2] = *(const f16x8*)(sBl_ + rb * 64 + rdoff);
            }
            if (do_stage) {  // stagger tile-t+2 staging: 2 gloads per phase
                if (ni == 0) STAGE_G0(Ls, go)
                else if (ni == 1) STAGE_G1(Ls, go)
                else if (ni == 2) STAGE_G2(Ls, go)
            }
            __builtin_amdgcn_sched_barrier(0);
            __builtin_amdgcn_s_setprio(1);
#pragma unroll
            for (int mi = 0; mi < 4; ++mi) {
                acc[mi][ni] = __builtin_amdgcn_mfma_f32_16x16x32_f16(ah[mi], bh[ni], acc[mi][ni], 0, 0, 0);
                accx[mi][ni] = __builtin_amdgcn_mfma_f32_16x16x32_f16(ah[mi], bl[ni], accx[mi][ni], 0, 0, 0);
                accx[mi][ni] = __builtin_amdgcn_mfma_f32_16x16x32_f16(al[mi], bh[ni], accx[mi][ni], 0, 0, 0);
            }
            __builtin_amdgcn_s_setprio(0);
        }
    }
#undef STAGE_G0
#undef STAGE_G1
#undef STAGE_G2

    // epilogue: combine split accumulators, optional relu, store fp32
#pragma unroll
    for (int mi = 0; mi < 4; ++mi)
#pragma unroll
        for (int ni = 0; ni < 4; ++ni) {
            int colx = col0 + wn * 64 + ni * 16 + lr;
            int rowb = row0 + wm * 64 + mi * 16 + ((lane >> 4) << 2);
#pragma unroll
            for (int r = 0; r < 4; ++r) {
                float v = acc[mi][ni][r] + accx[mi][ni][r] * (1.0f / 2048.0f);
                if (do_relu) v = fmaxf(v, 0.0f);
                C[(size_t)(rowb + r) * M + colx] = v;
            }
        }
}

// ---------------- small-M GEMM (layer 3, M=1024): proven 128x128 single-buffer kernel
__global__ __launch_bounds__(256, 2) void gemm3_kernel(
    const _Float16* __restrict__ Ah, const _Float16* __restrict__ Al,
    const _Float16* __restrict__ Bh, const _Float16* __restrict__ Bl,
    float* __restrict__ C, int K, int M, int do_relu) {
    __shared__ __align__(16) _Float16 sAh[128 * 32];
    __shared__ __align__(16) _Float16 sAl[128 * 32];
    __shared__ __align__(16) _Float16 sBh[128 * 32];
    __shared__ __align__(16) _Float16 sBl[128 * 32];

    const int tid = threadIdx.x;
    const int row0 = blockIdx.y * 128;
    const int col0 = blockIdx.x * 128;
    const int wid = tid >> 6, lane = tid & 63;
    const int wm = wid >> 1, wn = wid & 1;
    const int lr = lane & 15, lk = (lane >> 4) * 8;

    f32x4 acc[4][4] = {};
    f32x4 accx[4][4] = {};

    const int o0 = tid * 16;
    const int o1 = o0 + 4096;
    const int r0 = o0 >> 6, c0 = o0 & 63;
    const int r1 = o1 >> 6, c1 = o1 & 63;
    const size_t sk = (size_t)K * 2;

    const char* gAh0 = (const char*)Ah + (size_t)(row0 + r0) * sk + c0;
    const char* gAh1 = (const char*)Ah + (size_t)(row0 + r1) * sk + c1;
    const char* gAl0 = (const char*)Al + (size_t)(row0 + r0) * sk + c0;
    const char* gAl1 = (const char*)Al + (size_t)(row0 + r1) * sk + c1;
    const char* gBh0 = (const char*)Bh + (size_t)(col0 + r0) * sk + c0;
    const char* gBh1 = (const char*)Bh + (size_t)(col0 + r1) * sk + c1;
    const char* gBl0 = (const char*)Bl + (size_t)(col0 + r0) * sk + c0;
    const char* gBl1 = (const char*)Bl + (size_t)(col0 + r1) * sk + c1;

    for (int k0 = 0; k0 < K; k0 += 32) {
        __syncthreads();
        gload16(gAh0, (char*)sAh + o0);
        gload16(gAh1, (char*)sAh + o1);
        gload16(gAl0, (char*)sAl + o0);
        gload16(gAl1, (char*)sAl + o1);
        gload16(gBh0, (char*)sBh + o0);
        gload16(gBh1, (char*)sBh + o1);
        gload16(gBl0, (char*)sBl + o0);
        gload16(gBl1, (char*)sBl + o1);
        gAh0 += 64; gAh1 += 64; gAl0 += 64; gAl1 += 64;
        gBh0 += 64; gBh1 += 64; gBl0 += 64; gBl1 += 64;
        __syncthreads();

        f16x8 bh[4], bl[4];
#pragma unroll
        for (int ni = 0; ni < 4; ++ni) {
            int rb = wn * 64 + ni * 16 + lr;
            bh[ni] = *(const f16x8*)&sBh[rb * 32 + lk];
            bl[ni] = *(const f16x8*)&sBl[rb * 32 + lk];
        }
#pragma unroll
        for (int mi = 0; mi < 4; ++mi) {
            int ra = wm * 64 + mi * 16 + lr;
            f16x8 ah = *(const f16x8*)&sAh[ra * 32 + lk];
            f16x8 al = *(const f16x8*)&sAl[ra * 32 + lk];
#pragma unroll
            for (int ni = 0; ni < 4; ++ni) {
                acc[mi][ni] = __builtin_amdgcn_mfma_f32_16x16x32_f16(ah, bh[ni], acc[mi][ni], 0, 0, 0);
                accx[mi][ni] = __builtin_amdgcn_mfma_f32_16x16x32_f16(ah, bl[ni], accx[mi][ni], 0, 0, 0);
                accx[mi][ni] = __builtin_amdgcn_mfma_f32_16x16x32_f16(al, bh[ni], accx[mi][ni], 0, 0, 0);
            }
        }
    }
#pragma unroll
    for (int mi = 0; mi < 4; ++mi)
#pragma unroll
        for (int ni = 0; ni < 4; ++ni) {
            int colx = col0 + wn * 64 + ni * 16 + lr;
            int rowb = row0 + wm * 64 + mi * 16 + (lane >> 4) * 4;
#pragma unroll
            for (int r = 0; r < 4; ++r) {
                float v = acc[mi][ni][r] + accx[mi][ni][r] * (1.0f / 2048.0f);
                if (do_relu) v = fmaxf(v, 0.0f);
                C[(size_t)(rowb + r) * M + colx] = v;
            }
        }
}

// ---------------- kWTA: exact k-th largest of (x - thr[col]) per row via 4x8-bit radix
template <int CNT, bool SOFTMAX>
__global__ __launch_bounds__(256) void kwta_kernel(const float* __restrict__ Cin,
                                                   const float* __restrict__ thr,
                                                   _Float16* __restrict__ Oh,
                                                   _Float16* __restrict__ Ol,
                                                   float* __restrict__ outT, int M, int k) {
    const int row = blockIdx.x, tid = threadIdx.x;
    const float* rp = Cin + (size_t)row * M;
    unsigned uv[CNT];
    float xv[CNT];
#pragma unroll
    for (int i = 0; i < CNT; ++i) {
        int col = i * 256 + tid;
        float x = rp[col];
        float a = x - thr[col];
        unsigned b = __float_as_uint(a);
        uv[i] = (b & 0x80000000u) ? ~b : (b | 0x80000000u);
        xv[i] = x;
    }
    __shared__ int hist[256];
    __shared__ unsigned sel_s;
    __shared__ int kk_s;
    unsigned prefix = 0;
    int kk = k;
#pragma unroll
    for (int pass = 0; pass < 4; ++pass) {
        const int shift = 24 - pass * 8;
        hist[tid] = 0;
        __syncthreads();
#pragma unroll
        for (int i = 0; i < CNT; ++i) {
            bool ok = (pass == 0) || ((uv[i] >> (shift + 8)) == prefix);
            if (ok) atomicAdd(&hist[(uv[i] >> shift) & 255], 1);
        }
        __syncthreads();
        for (int off = 1; off < 256; off <<= 1) {
            int v = hist[tid] + ((tid + off < 256) ? hist[tid + off] : 0);
            __syncthreads();
            hist[tid] = v;
            __syncthreads();
        }
        if (hist[tid] >= kk && (tid == 255 || hist[tid + 1] < kk)) {
            sel_s = (unsigned)tid;
            kk_s = kk - ((tid == 255) ? 0 : hist[tid + 1]);
        }
        __syncthreads();
        prefix = (prefix << 8) | sel_s;
        kk = kk_s;
        __syncthreads();
    }
    const unsigned kth = prefix;
    if (!SOFTMAX) {
#pragma unroll
        for (int i = 0; i < CNT; ++i) {
            int col = i * 256 + tid;
            float v = (uv[i] >= kth) ? xv[i] : 0.0f;
            size_t idx = (size_t)row * M + col;
            _Float16 h = (_Float16)v;
            Oh[idx] = h;
            Ol[idx] = (_Float16)((v - (float)h) * 2048.0f);
        }
    } else {
        float vals[CNT];
        float m = -3.4e38f;
#pragma unroll
        for (int i = 0; i < CNT; ++i) {
            float v = (uv[i] >= kth) ? xv[i] : 0.0f;
            vals[i] = v;
            m = fmaxf(m, v);
        }
        for (int off = 32; off; off >>= 1) m = fmaxf(m, __shfl_xor(m, off));
        __shared__ float redm[4];
        if ((tid & 63) == 0) redm[tid >> 6] = m;
        __syncthreads();
        m = fmaxf(fmaxf(redm[0], redm[1]), fmaxf(redm[2], redm[3]));
        float s = 0.0f, e[CNT];
#pragma unroll
        for (int i = 0; i < CNT; ++i) {
            e[i] = expf(vals[i] - m);
            s += e[i];
        }
        for (int off = 32; off; off >>= 1) s += __shfl_xor(s, off);
        __shared__ float reds[4];
        if ((tid & 63) == 0) reds[tid >> 6] = s;
        __syncthreads();
        s = reds[0] + reds[1] + reds[2] + reds[3];
        float inv = 1.0f / s;
#pragma unroll
        for (int i = 0; i < CNT; ++i)
            outT[(size_t)(i * 256 + tid) * NB + row] = e[i] * inv;
    }
}

extern "C" void kernel_launch(void* const* d_in, const int* in_sizes, int n_in,
                              void* d_out, int out_size, void* d_ws, size_t ws_size,
                              hipStream_t stream) {
    const float* x = (const float*)d_in[0];
    const float* W0 = (const float*)d_in[1];
    const float* thr0 = (const float*)d_in[2];
    const float* W1 = (const float*)d_in[3];
    const float* thr1 = (const float*)d_in[4];
    const float* W2 = (const float*)d_in[5];
    const float* thr2 = (const float*)d_in[6];
    const float* W3 = (const float*)d_in[7];
    const float* thr3 = (const float*)d_in[8];
    float* out = (float*)d_out;

    char* ws = (char*)d_ws;
    size_t off = 0;
    auto alloc = [&](size_t bytes) {
        void* p = ws + off;
        off += (bytes + 255) & ~(size_t)255;
        return p;
    };
    _Float16* Wh = (_Float16*)alloc((size_t)8192 * 8192 * 2);
    _Float16* Wl = (_Float16*)alloc((size_t)8192 * 8192 * 2);
    _Float16* Xh = (_Float16*)alloc((size_t)4096 * 8192 * 2);
    _Float16* Xl = (_Float16*)alloc((size_t)4096 * 8192 * 2);
    _Float16* Yh = (_Float16*)alloc((size_t)4096 * 8192 * 2);
    _Float16* Yl = (_Float16*)alloc((size_t)4096 * 8192 * 2);
    float* C32 = (float*)alloc((size_t)4096 * 8192 * 4);

    tsplit_kernel<<<dim3(64, 64), 256, 0, stream>>>(x, Xh, Xl);

    // layer 0: K=4096, M=8192, relu, k=409
    splitw_kernel<<<4096, 256, 0, stream>>>(W0, Wh, Wl, (long)8192 * 4096 / 4);
    gemm3p_kernel<<<dim3(8192 / 256, NB / 128), 512, 0, stream>>>(Xh, Xl, Wh, Wl, C32, 4096, 8192, 1);
    kwta_kernel<32, false><<<NB, 256, 0, stream>>>(C32, thr0, Yh, Yl, nullptr, 8192, 409);

    // layer 1: K=8192, M=8192, relu, k=409
    splitw_kernel<<<4096, 256, 0, stream>>>(W1, Wh, Wl, (long)8192 * 8192 / 4);
    gemm3p_kernel<<<dim3(8192 / 256, NB / 128), 512, 0, stream>>>(Yh, Yl, Wh, Wl, C32, 8192, 8192, 1);
    kwta_kernel<32, false><<<NB, 256, 0, stream>>>(C32, thr1, Xh, Xl, nullptr, 8192, 409);

    // layer 2: K=8192, M=4096, relu, k=204
    splitw_kernel<<<4096, 256, 0, stream>>>(W2, Wh, Wl, (long)4096 * 8192 / 4);
    gemm3p_kernel<<<dim3(4096 / 256, NB / 128), 512, 0, stream>>>(Xh, Xl, Wh, Wl, C32, 8192, 4096, 1);
    kwta_kernel<16, false><<<NB, 256, 0, stream>>>(C32, thr2, Yh, Yl, nullptr, 4096, 204);

    // layer 3: K=4096, M=1024, no relu, k=51, then softmax -> out [1024][4096]
    splitw_kernel<<<4096, 256, 0, stream>>>(W3, Wh, Wl, (long)1024 * 4096 / 4);
    gemm3_kernel<<<dim3(1024 / 128, NB / 128), 256, 0, stream>>>(Yh, Yl, Wh, Wl, C32, 4096, 1024, 0);
    kwta_kernel<4, true><<<NB, 256, 0, stream>>>(C32, thr3, nullptr, nullptr, out, 1024, 51);
}

// Round 4
// 3254.593 us; speedup vs baseline: 1.6108x; 1.0119x over previous
//
#include <hip/hip_runtime.h>

typedef _Float16 f16x8 __attribute__((ext_vector_type(8)));
typedef _Float16 f16x4 __attribute__((ext_vector_type(4)));
typedef float f32x4 __attribute__((ext_vector_type(4)));

#define NB 4096  // batch

__device__ __forceinline__ void gload16(const void* g, void* l) {
    __builtin_amdgcn_global_load_lds(
        (const __attribute__((address_space(1))) unsigned int*)g,
        (__attribute__((address_space(3))) unsigned int*)l, 16, 0, 0);
}

// ---------------- transpose + fp16-split of initial x: [4096 f][4096 b] -> Xt[b][f] h/l
__global__ __launch_bounds__(256) void tsplit_kernel(const float* __restrict__ X,
                                                     _Float16* __restrict__ Oh,
                                                     _Float16* __restrict__ Ol) {
    __shared__ float t[64][65];
    const int f0 = blockIdx.x * 64, b0 = blockIdx.y * 64;
    const int tid = threadIdx.x;
    const int jj = tid & 63, i0 = tid >> 6;
#pragma unroll
    for (int p = 0; p < 16; ++p) {
        int i = p * 4 + i0;
        t[i][jj] = X[(size_t)(f0 + i) * NB + b0 + jj];
    }
    __syncthreads();
#pragma unroll
    for (int p = 0; p < 16; ++p) {
        int b = p * 4 + i0;
        float v = t[jj][b];
        size_t idx = (size_t)(b0 + b) * 4096 + f0 + jj;
        _Float16 h = (_Float16)v;
        Oh[idx] = h;
        Ol[idx] = (_Float16)((v - (float)h) * 2048.0f);
    }
}

// ---------------- fp16-split of a weight matrix (elementwise)
__global__ __launch_bounds__(256) void splitw_kernel(const float* __restrict__ W,
                                                     _Float16* __restrict__ Wh,
                                                     _Float16* __restrict__ Wl, long n4) {
    long i = (long)blockIdx.x * 256 + threadIdx.x;
    const long stride = (long)gridDim.x * 256;
    for (; i < n4; i += stride) {
        float4 w = ((const float4*)W)[i];
        float vs[4] = {w.x, w.y, w.z, w.w};
        f16x4 h, l;
#pragma unroll
        for (int j = 0; j < 4; ++j) {
            _Float16 hh = (_Float16)vs[j];
            h[j] = hh;
            l[j] = (_Float16)((vs[j] - (float)hh) * 2048.0f);
        }
        ((f16x4*)Wh)[i] = h;
        ((f16x4*)Wl)[i] = l;
    }
}

// ---------------- pipelined GEMM: C[batch][M] = Xt @ W^T, fp16x2-split 3-MFMA
// Tile 128(batch) x 256(feat), BK=32, 512 thr = 8 waves (2M x 4N), per-wave 64x64.
// Triple-buffered LDS, depth-2 prefetch with counted vmcnt, T2 XOR swizzle, T5 setprio,
// L3 supertile block remap, and diagonal read/MFMA interleave (4 read-groups of 4,
// MFMA cluster steps 1/3/5/7 ordered by data availability) so LDS reads of later
// groups hide under earlier MFMA steps.
__global__ __launch_bounds__(512, 2) void gemm3p_kernel(
    const _Float16* __restrict__ Ah, const _Float16* __restrict__ Al,
    const _Float16* __restrict__ Bh, const _Float16* __restrict__ Bl,
    float* __restrict__ C, int K, int M, int do_relu) {
    // per buffer: A h 8KB | A l 8KB | B h 16KB | B l 16KB = 48KB; x3 = 144KB
    __shared__ __align__(16) char lds[3][49152];

    const int tid = threadIdx.x;
    const int gx = gridDim.x;
    // supertile remap: 256 consecutive hw bids -> SC col-tiles x SR row-tiles square
    int bid = blockIdx.y * gx + blockIdx.x;
    const int SC = gx < 16 ? gx : 16;
    const int SR = 256 / SC;
    const int nsc = gx / SC;
    const int s = bid >> 8, w = bid & 255;
    const int col0 = ((s % nsc) * SC + (w % SC)) * 256;  // feature cols
    const int row0 = ((s / nsc) * SR + (w / SC)) * 128;  // batch rows

    const int wid = tid >> 6, lane = tid & 63;
    const int wm = wid >> 2, wn = wid & 3;  // 2 x 4 waves
    const int lr = lane & 15;
    // read-side swizzle: per-lane 16B chunk within a 64B row: chunk' = c ^ ((row>>1)&3)
    const int rdoff = (((lane >> 4) ^ ((lane >> 1) & 3)) << 4);

    f32x4 acc[4][4] = {};
    f32x4 accx[4][4] = {};

    // staging: linear LDS dest (tid*16); inverse-swizzled global source chunk
    const int srow = tid >> 2;                     // local row 0..127
    const int scl = (tid & 3) ^ ((tid >> 3) & 3);  // logical k-chunk for this dest
    const size_t sk = (size_t)K;
    const _Float16* gA_h = Ah + (size_t)(row0 + srow) * sk + scl * 8;
    const _Float16* gA_l = Al + (size_t)(row0 + srow) * sk + scl * 8;
    const _Float16* gB_h0 = Bh + (size_t)(col0 + srow) * sk + scl * 8;
    const _Float16* gB_h1 = Bh + (size_t)(col0 + 128 + srow) * sk + scl * 8;
    const _Float16* gB_l0 = Bl + (size_t)(col0 + srow) * sk + scl * 8;
    const _Float16* gB_l1 = Bl + (size_t)(col0 + 128 + srow) * sk + scl * 8;
    const int ldsA = tid * 16;

#define STAGE_G0(Lb, go) { gload16(gA_h + go, (Lb) + ldsA); gload16(gA_l + go, (Lb) + 8192 + ldsA); }
#define STAGE_G1(Lb, go) { gload16(gB_h0 + go, (Lb) + 16384 + ldsA); gload16(gB_h1 + go, (Lb) + 24576 + ldsA); }
#define STAGE_G2(Lb, go) { gload16(gB_l0 + go, (Lb) + 32768 + ldsA); gload16(gB_l1 + go, (Lb) + 40960 + ldsA); }

    const int NT = K / 32;
    {  // prologue: tiles 0 and 1, 6 loads each in program-order groups
        STAGE_G0(lds[0], 0); STAGE_G1(lds[0], 0); STAGE_G2(lds[0], 0);
        STAGE_G0(lds[1], 32); STAGE_G1(lds[1], 32); STAGE_G2(lds[1], 32);
    }

    for (int t = 0; t < NT; ++t) {
        if (t < NT - 1) {
            asm volatile("s_waitcnt vmcnt(6)" ::: "memory");  // tile t landed; t+1 in flight
        } else {
            asm volatile("s_waitcnt vmcnt(0)" ::: "memory");
        }
        __builtin_amdgcn_s_barrier();
        asm volatile("" ::: "memory");  // keep LDS/VMEM ops below the barrier

        const char* Lb = lds[t % 3];
        char* Ls = lds[(t + 2) % 3];               // stage dest (last read in iter t-1)
        const bool do_stage = (t + 2 < NT);
        const size_t go = (size_t)(t + 2) * 32;

        const char* sAh_ = Lb;
        const char* sAl_ = Lb + 8192;
        const char* sBh_ = Lb + 16384;
        const char* sBl_ = Lb + 32768;

        f16x8 ah[4], al[4], bh[4], bl[4];
#define READG(i)                                                              \
    {                                                                         \
        const int ra = wm * 64 + (i)*16 + lr;                                 \
        const int rb = wn * 64 + (i)*16 + lr;                                 \
        ah[i] = *(const f16x8*)(sAh_ + ra * 64 + rdoff);                      \
        al[i] = *(const f16x8*)(sAl_ + ra * 64 + rdoff);                      \
        bh[i] = *(const f16x8*)(sBh_ + rb * 64 + rdoff);                      \
        bl[i] = *(const f16x8*)(sBl_ + rb * 64 + rdoff);                      \
    }
#define CL(mi, ni)                                                                               \
    {                                                                                            \
        acc[mi][ni] = __builtin_amdgcn_mfma_f32_16x16x32_f16(ah[mi], bh[ni], acc[mi][ni], 0, 0, 0);  \
        accx[mi][ni] = __builtin_amdgcn_mfma_f32_16x16x32_f16(ah[mi], bl[ni], accx[mi][ni], 0, 0, 0); \
        accx[mi][ni] = __builtin_amdgcn_mfma_f32_16x16x32_f16(al[mi], bh[ni], accx[mi][ni], 0, 0, 0); \
    }
        READG(0)
        READG(1)
        asm volatile("s_waitcnt lgkmcnt(4)" ::: "memory");  // G0 ready, G1 in flight
        __builtin_amdgcn_sched_barrier(0);
        __builtin_amdgcn_s_setprio(1);
        CL(0, 0)
        __builtin_amdgcn_s_setprio(0);

        READG(2)
        if (do_stage) STAGE_G0(Ls, go);
        asm volatile("s_waitcnt lgkmcnt(4)" ::: "memory");  // G1 ready, G2 in flight
        __builtin_amdgcn_sched_barrier(0);
        __builtin_amdgcn_s_setprio(1);
        CL(0, 1) CL(1, 0) CL(1, 1)
        __builtin_amdgcn_s_setprio(0);

        READG(3)
        if (do_stage) STAGE_G1(Ls, go);
        asm volatile("s_waitcnt lgkmcnt(4)" ::: "memory");  // G2 ready, G3 in flight
        __builtin_amdgcn_sched_barrier(0);
        __builtin_amdgcn_s_setprio(1);
        CL(0, 2) CL(1, 2) CL(2, 0) CL(2, 1) CL(2, 2)
        __builtin_amdgcn_s_setprio(0);

        if (do_stage) STAGE_G2(Ls, go);
        asm volatile("s_waitcnt lgkmcnt(0)" ::: "memory");  // G3 ready; all reads drained
        __builtin_amdgcn_sched_barrier(0);
        __builtin_amdgcn_s_setprio(1);
        CL(0, 3) CL(1, 3) CL(2, 3) CL(3, 0) CL(3, 1) CL(3, 2) CL(3, 3)
        __builtin_amdgcn_s_setprio(0);
#undef READG
#undef CL
    }
#undef STAGE_G0
#undef STAGE_G1
#undef STAGE_G2

    // epilogue: combine split accumulators, optional relu, store fp32
#pragma unroll
    for (int mi = 0; mi < 4; ++mi)
#pragma unroll
        for (int ni = 0; ni < 4; ++ni) {
            int colx = col0 + wn * 64 + ni * 16 + lr;
            int rowb = row0 + wm * 64 + mi * 16 + ((lane >> 4) << 2);
#pragma unroll
            for (int r = 0; r < 4; ++r) {
                float v = acc[mi][ni][r] + accx[mi][ni][r] * (1.0f / 2048.0f);
                if (do_relu) v = fmaxf(v, 0.0f);
                C[(size_t)(rowb + r) * M + colx] = v;
            }
        }
}

// ---------------- kWTA: exact k-th largest of (x - thr[col]) per row via 4x8-bit radix
template <int CNT, bool SOFTMAX>
__global__ __launch_bounds__(256) void kwta_kernel(const float* __restrict__ Cin,
                                                   const float* __restrict__ thr,
                                                   _Float16* __restrict__ Oh,
                                                   _Float16* __restrict__ Ol,
                                                   float* __restrict__ outT, int M, int k) {
    const int row = blockIdx.x, tid = threadIdx.x;
    const float* rp = Cin + (size_t)row * M;
    unsigned uv[CNT];
    float xv[CNT];
#pragma unroll
    for (int i = 0; i < CNT; ++i) {
        int col = i * 256 + tid;
        float x = rp[col];
        float a = x - thr[col];
        unsigned b = __float_as_uint(a);
        uv[i] = (b & 0x80000000u) ? ~b : (b | 0x80000000u);
        xv[i] = x;
    }
    __shared__ int hist[256];
    __shared__ unsigned sel_s;
    __shared__ int kk_s;
    unsigned prefix = 0;
    int kk = k;
#pragma unroll
    for (int pass = 0; pass < 4; ++pass) {
        const int shift = 24 - pass * 8;
        hist[tid] = 0;
        __syncthreads();
#pragma unroll
        for (int i = 0; i < CNT; ++i) {
            bool ok = (pass == 0) || ((uv[i] >> (shift + 8)) == prefix);
            if (ok) atomicAdd(&hist[(uv[i] >> shift) & 255], 1);
        }
        __syncthreads();
        for (int off = 1; off < 256; off <<= 1) {
            int v = hist[tid] + ((tid + off < 256) ? hist[tid + off] : 0);
            __syncthreads();
            hist[tid] = v;
            __syncthreads();
        }
        if (hist[tid] >= kk && (tid == 255 || hist[tid + 1] < kk)) {
            sel_s = (unsigned)tid;
            kk_s = kk - ((tid == 255) ? 0 : hist[tid + 1]);
        }
        __syncthreads();
        prefix = (prefix << 8) | sel_s;
        kk = kk_s;
        __syncthreads();
    }
    const unsigned kth = prefix;
    if (!SOFTMAX) {
#pragma unroll
        for (int i = 0; i < CNT; ++i) {
            int col = i * 256 + tid;
            float v = (uv[i] >= kth) ? xv[i] : 0.0f;
            size_t idx = (size_t)row * M + col;
            _Float16 h = (_Float16)v;
            Oh[idx] = h;
            Ol[idx] = (_Float16)((v - (float)h) * 2048.0f);
        }
    } else {
        float vals[CNT];
        float m = -3.4e38f;
#pragma unroll
        for (int i = 0; i < CNT; ++i) {
            float v = (uv[i] >= kth) ? xv[i] : 0.0f;
            vals[i] = v;
            m = fmaxf(m, v);
        }
        for (int off = 32; off; off >>= 1) m = fmaxf(m, __shfl_xor(m, off));
        __shared__ float redm[4];
        if ((tid & 63) == 0) redm[tid >> 6] = m;
        __syncthreads();
        m = fmaxf(fmaxf(redm[0], redm[1]), fmaxf(redm[2], redm[3]));
        float s = 0.0f, e[CNT];
#pragma unroll
        for (int i = 0; i < CNT; ++i) {
            e[i] = expf(vals[i] - m);
            s += e[i];
        }
        for (int off = 32; off; off >>= 1) s += __shfl_xor(s, off);
        __shared__ float reds[4];
        if ((tid & 63) == 0) reds[tid >> 6] = s;
        __syncthreads();
        s = reds[0] + reds[1] + reds[2] + reds[3];
        float inv = 1.0f / s;
#pragma unroll
        for (int i = 0; i < CNT; ++i)
            outT[(size_t)(i * 256 + tid) * NB + row] = e[i] * inv;
    }
}

extern "C" void kernel_launch(void* const* d_in, const int* in_sizes, int n_in,
                              void* d_out, int out_size, void* d_ws, size_t ws_size,
                              hipStream_t stream) {
    const float* x = (const float*)d_in[0];
    const float* W0 = (const float*)d_in[1];
    const float* thr0 = (const float*)d_in[2];
    const float* W1 = (const float*)d_in[3];
    const float* thr1 = (const float*)d_in[4];
    const float* W2 = (const float*)d_in[5];
    const float* thr2 = (const float*)d_in[6];
    const float* W3 = (const float*)d_in[7];
    const float* thr3 = (const float*)d_in[8];
    float* out = (float*)d_out;

    char* ws = (char*)d_ws;
    size_t off = 0;
    auto alloc = [&](size_t bytes) {
        void* p = ws + off;
        off += (bytes + 255) & ~(size_t)255;
        return p;
    };
    _Float16* Wh = (_Float16*)alloc((size_t)8192 * 8192 * 2);
    _Float16* Wl = (_Float16*)alloc((size_t)8192 * 8192 * 2);
    _Float16* Xh = (_Float16*)alloc((size_t)4096 * 8192 * 2);
    _Float16* Xl = (_Float16*)alloc((size_t)4096 * 8192 * 2);
    _Float16* Yh = (_Float16*)alloc((size_t)4096 * 8192 * 2);
    _Float16* Yl = (_Float16*)alloc((size_t)4096 * 8192 * 2);
    float* C32 = (float*)alloc((size_t)4096 * 8192 * 4);

    tsplit_kernel<<<dim3(64, 64), 256, 0, stream>>>(x, Xh, Xl);

    // layer 0: K=4096, M=8192, relu, k=409
    splitw_kernel<<<4096, 256, 0, stream>>>(W0, Wh, Wl, (long)8192 * 4096 / 4);
    gemm3p_kernel<<<dim3(8192 / 256, NB / 128), 512, 0, stream>>>(Xh, Xl, Wh, Wl, C32, 4096, 8192, 1);
    kwta_kernel<32, false><<<NB, 256, 0, stream>>>(C32, thr0, Yh, Yl, nullptr, 8192, 409);

    // layer 1: K=8192, M=8192, relu, k=409
    splitw_kernel<<<4096, 256, 0, stream>>>(W1, Wh, Wl, (long)8192 * 8192 / 4);
    gemm3p_kernel<<<dim3(8192 / 256, NB / 128), 512, 0, stream>>>(Yh, Yl, Wh, Wl, C32, 8192, 8192, 1);
    kwta_kernel<32, false><<<NB, 256, 0, stream>>>(C32, thr1, Xh, Xl, nullptr, 8192, 409);

    // layer 2: K=8192, M=4096, relu, k=204
    splitw_kernel<<<4096, 256, 0, stream>>>(W2, Wh, Wl, (long)4096 * 8192 / 4);
    gemm3p_kernel<<<dim3(4096 / 256, NB / 128), 512, 0, stream>>>(Xh, Xl, Wh, Wl, C32, 8192, 4096, 1);
    kwta_kernel<16, false><<<NB, 256, 0, stream>>>(C32, thr2, Yh, Yl, nullptr, 4096, 204);

    // layer 3: K=4096, M=1024, no relu, k=51, then softmax -> out [1024][4096]
    splitw_kernel<<<4096, 256, 0, stream>>>(W3, Wh, Wl, (long)1024 * 4096 / 4);
    gemm3p_kernel<<<dim3(1024 / 256, NB / 128), 512, 0, stream>>>(Yh, Yl, Wh, Wl, C32, 4096, 1024, 0);
    kwta_kernel<4, true><<<NB, 256, 0, stream>>>(C32, thr3, nullptr, nullptr, out, 1024, 51);
}